// Round 1
// baseline (341.088 us; speedup 1.0000x reference)
//
#include <hip/hip_runtime.h>

#define DIM 1024
#define NH 8
#define HD 128
#define T_SEQ 2048
#define BATCH 4
#define NTOK (BATCH*T_SEQ)     // 8192
#define QKV_N (3*NH*HD)        // 3072
#define ATTN_SCALE 0.12f
#define RMS_EPS 1.1920929e-07f

using f32x4  = __attribute__((ext_vector_type(4))) float;
using bf16x8 = __attribute__((ext_vector_type(8))) __bf16;

__device__ __forceinline__ unsigned short f2bf(float f) {
    unsigned int u = __builtin_bit_cast(unsigned int, f);
    u += 0x7fffu + ((u >> 16) & 1u);           // RNE
    return (unsigned short)(u >> 16);
}
__device__ __forceinline__ float bf2f(unsigned short s) {
    unsigned int u = ((unsigned int)s) << 16;
    return __builtin_bit_cast(float, u);
}

// ---------------------------------------------------------------- conversions
__global__ __launch_bounds__(256) void cvt_f32_bf16(const float* __restrict__ in,
                                                    unsigned short* __restrict__ out,
                                                    int n4) {
    int i = blockIdx.x * 256 + threadIdx.x;
    if (i < n4) {
        float4 f = ((const float4*)in)[i];
        ushort4 o;
        o.x = f2bf(f.x); o.y = f2bf(f.y); o.z = f2bf(f.z); o.w = f2bf(f.w);
        ((ushort4*)out)[i] = o;
    }
}

// ---------------------------------------------------------------- GEMM  C = A * B^T
// A: M x K row-major bf16, B: N x K row-major bf16 (i.e. weights), K % 32 == 0,
// M,N % 128 == 0. 128x128 tile, 4 waves (2x2), each wave 64x64 (4x4 MFMA frags).
#define LDP 40   // padded LDS row stride (32 data + 8 pad) -> 2-way-free banks

template<int OUTF32>
__global__ __launch_bounds__(256) void gemm_bt(const unsigned short* __restrict__ A,
                                               const unsigned short* __restrict__ B,
                                               void* __restrict__ Cout,
                                               int M, int N, int K) {
    __shared__ unsigned short lA[128*LDP];
    __shared__ unsigned short lB[128*LDP];
    const int tid  = threadIdx.x;
    const int lane = tid & 63;
    const int w    = tid >> 6;
    const int wm   = w >> 1, wn = w & 1;
    const int lr   = lane & 15, lg = lane >> 4;
    const int m0   = blockIdx.y * 128;
    const int n0   = blockIdx.x * 128;

    f32x4 acc[4][4] = {};

    for (int k0 = 0; k0 < K; k0 += 32) {
        __syncthreads();
        #pragma unroll
        for (int rep = 0; rep < 2; ++rep) {
            int v   = rep*256 + tid;        // 0..511 vec16B ids
            int row = v >> 2;               // 0..127
            int col = (v & 3) << 3;         // 0,8,16,24
            *(uint4*)&lA[row*LDP + col] = *(const uint4*)&A[(size_t)(m0+row)*K + k0 + col];
            *(uint4*)&lB[row*LDP + col] = *(const uint4*)&B[(size_t)(n0+row)*K + k0 + col];
        }
        __syncthreads();
        bf16x8 af[4], bfr[4];
        #pragma unroll
        for (int i = 0; i < 4; ++i)
            af[i]  = *(const bf16x8*)&lA[(wm*64 + i*16 + lr)*LDP + lg*8];
        #pragma unroll
        for (int j = 0; j < 4; ++j)
            bfr[j] = *(const bf16x8*)&lB[(wn*64 + j*16 + lr)*LDP + lg*8];
        #pragma unroll
        for (int i = 0; i < 4; ++i)
            #pragma unroll
            for (int j = 0; j < 4; ++j)
                acc[i][j] = __builtin_amdgcn_mfma_f32_16x16x32_bf16(af[i], bfr[j], acc[i][j], 0, 0, 0);
    }

    #pragma unroll
    for (int i = 0; i < 4; ++i)
        #pragma unroll
        for (int j = 0; j < 4; ++j)
            #pragma unroll
            for (int r = 0; r < 4; ++r) {
                int row = m0 + wm*64 + i*16 + lg*4 + r;
                int col = n0 + wn*64 + j*16 + lr;
                if (OUTF32) ((float*)Cout)[(size_t)row*N + col] = acc[i][j][r];
                else ((unsigned short*)Cout)[(size_t)row*N + col] = f2bf(acc[i][j][r]);
            }
}

// ---------------------------------------------------------------- post: RMSNorm+RoPE+vmix
// one wave per (token, head); lane l owns dims l and l+64 (the RoPE pair).
__global__ __launch_bounds__(256) void qkv_post(const unsigned short* __restrict__ qkv,
                                                const float* __restrict__ ve,
                                                const float* __restrict__ lam,
                                                unsigned short* __restrict__ qO,
                                                unsigned short* __restrict__ kO,
                                                unsigned short* __restrict__ vtO) {
    int gw   = (blockIdx.x * 256 + threadIdx.x) >> 6;   // 0..65535
    int lane = threadIdx.x & 63;
    int h     = gw & 7;
    int token = gw >> 3;            // 0..8191
    int t     = token & (T_SEQ-1);
    int b     = token >> 11;

    const unsigned short* base = qkv + (size_t)token * QKV_N + h*HD;
    float q1 = bf2f(base[lane]),        q2 = bf2f(base[lane+64]);
    float k1 = bf2f(base[1024+lane]),   k2 = bf2f(base[1024+lane+64]);
    float v1 = bf2f(base[2048+lane]),   v2 = bf2f(base[2048+lane+64]);

    float sq = q1*q1 + q2*q2;
    float sk = k1*k1 + k2*k2;
    #pragma unroll
    for (int m = 1; m < 64; m <<= 1) {
        sq += __shfl_xor(sq, m);
        sk += __shfl_xor(sk, m);
    }
    float qs = rsqrtf(sq * (1.0f/128.0f) + RMS_EPS);
    float ks = rsqrtf(sk * (1.0f/128.0f) + RMS_EPS);
    q1 *= qs; q2 *= qs; k1 *= ks; k2 *= ks;

    // theta = t * 1024^(-lane/31) for lane<32, else 0 (identity rotation)
    float theta = (lane < 32) ? (float)t * exp2f((float)lane * (-10.0f/31.0f)) : 0.0f;
    float sn, cs;
    sincosf(theta, &sn, &cs);   // precise path: theta up to 2047 rad
    float qy1 =  q1*cs + q2*sn, qy2 = -q1*sn + q2*cs;
    float ky1 =  k1*cs + k2*sn, ky2 = -k1*sn + k2*cs;

    size_t obase = ((size_t)(b*NH + h) * T_SEQ + t) * HD;
    qO[obase + lane]      = f2bf(qy1);
    qO[obase + lane + 64] = f2bf(qy2);
    kO[obase + lane]      = f2bf(ky1);
    kO[obase + lane + 64] = f2bf(ky2);

    float l0 = lam[0], l1 = lam[1];
    const float* veb = ve + (size_t)token * DIM + h*HD;
    float w1 = l0*v1 + l1*veb[lane];
    float w2 = l0*v2 + l1*veb[lane+64];
    size_t vtb = (size_t)(b*NH + h) * HD * T_SEQ + t;   // transposed: [bh][d][t]
    vtO[vtb + (size_t)lane*T_SEQ]      = f2bf(w1);
    vtO[vtb + (size_t)(lane+64)*T_SEQ] = f2bf(w2);
}

// ---------------------------------------------------------------- flash attention
// grid (T/64, B*H); 4 waves x 16 q-rows; KBLK=64; padded LDS (2-way-free banks).
#define LKP 136   // K tile row stride (128 + 8)
#define LVP 72    // Vt tile row stride (64 + 8)
#define LPP 72    // P tile row stride (64 + 8)

__global__ __launch_bounds__(256) void attn_fwd(const unsigned short* __restrict__ Q,
                                                const unsigned short* __restrict__ K,
                                                const unsigned short* __restrict__ Vt,
                                                unsigned short* __restrict__ Y) {
    __shared__ unsigned short lK[64*LKP];      // [k][d]
    __shared__ unsigned short lV[128*LVP];     // [d][k]   (V transposed)
    __shared__ unsigned short lP[4][16*LPP];   // per-wave [q][k]

    const int tid  = threadIdx.x;
    const int lane = tid & 63;
    const int w    = tid >> 6;
    const int lr   = lane & 15, lg = lane >> 4;
    const int bh   = blockIdx.y;
    const int qt   = blockIdx.x;
    const unsigned short* Qg = Q  + (size_t)bh * T_SEQ * HD;
    const unsigned short* Kg = K  + (size_t)bh * T_SEQ * HD;
    const unsigned short* Vg = Vt + (size_t)bh * HD * T_SEQ;
    const int q0 = qt*64 + w*16;

    bf16x8 qf[4];
    #pragma unroll
    for (int kk = 0; kk < 4; ++kk)
        qf[kk] = *(const bf16x8*)&Qg[(size_t)(q0 + lr)*HD + kk*32 + lg*8];

    f32x4 o[8] = {};
    float mrow[4] = {-INFINITY,-INFINITY,-INFINITY,-INFINITY};
    float lsum[4] = {0.f,0.f,0.f,0.f};

    const int nkt = qt + 1;
    for (int kt = 0; kt < nkt; ++kt) {
        const int kbase = kt * 64;
        __syncthreads();
        #pragma unroll
        for (int it = 0; it < 4; ++it) {           // K tile: 64 x 128
            int idx = it*256 + tid;
            int row = idx >> 4;
            int col = (idx & 15) << 3;
            *(uint4*)&lK[row*LKP + col] = *(const uint4*)&Kg[(size_t)(kbase+row)*HD + col];
        }
        #pragma unroll
        for (int it = 0; it < 4; ++it) {           // Vt tile: 128 x 64
            int idx = it*256 + tid;
            int row = idx >> 3;
            int col = (idx & 7) << 3;
            *(uint4*)&lV[row*LVP + col] = *(const uint4*)&Vg[(size_t)row*T_SEQ + kbase + col];
        }
        __syncthreads();

        if (kbase <= q0 + 15) {                    // wave-uniform: skip fully-masked tiles
            f32x4 sf[4];
            #pragma unroll
            for (int j = 0; j < 4; ++j) {
                f32x4 s = {0.f,0.f,0.f,0.f};
                #pragma unroll
                for (int kk = 0; kk < 4; ++kk) {
                    bf16x8 kf = *(const bf16x8*)&lK[(j*16+lr)*LKP + kk*32 + lg*8];
                    s = __builtin_amdgcn_mfma_f32_16x16x32_bf16(qf[kk], kf, s, 0, 0, 0);
                }
                sf[j] = s;
            }
            float pmax[4] = {-INFINITY,-INFINITY,-INFINITY,-INFINITY};
            #pragma unroll
            for (int j = 0; j < 4; ++j)
                #pragma unroll
                for (int r = 0; r < 4; ++r) {
                    float v = sf[j][r] * ATTN_SCALE;
                    int kcol = kbase + j*16 + lr;
                    int qrow = q0 + lg*4 + r;
                    v = (kcol > qrow) ? -INFINITY : v;
                    sf[j][r] = v;
                    pmax[r] = fmaxf(pmax[r], v);
                }
            #pragma unroll
            for (int m = 1; m < 16; m <<= 1)
                #pragma unroll
                for (int r = 0; r < 4; ++r)
                    pmax[r] = fmaxf(pmax[r], __shfl_xor(pmax[r], m));
            float resc[4];
            #pragma unroll
            for (int r = 0; r < 4; ++r) {
                float mn = fmaxf(mrow[r], pmax[r]);
                resc[r] = __expf(mrow[r] - mn);    // exp(-inf)=0 on first tile
                mrow[r] = mn;
            }
            float rs[4] = {0.f,0.f,0.f,0.f};
            #pragma unroll
            for (int j = 0; j < 4; ++j)
                #pragma unroll
                for (int r = 0; r < 4; ++r) {
                    float p = __expf(sf[j][r] - mrow[r]);
                    sf[j][r] = p;
                    rs[r] += p;
                }
            #pragma unroll
            for (int m = 1; m < 16; m <<= 1)
                #pragma unroll
                for (int r = 0; r < 4; ++r)
                    rs[r] += __shfl_xor(rs[r], m);
            #pragma unroll
            for (int r = 0; r < 4; ++r)
                lsum[r] = lsum[r]*resc[r] + rs[r];
            #pragma unroll
            for (int n = 0; n < 8; ++n)
                #pragma unroll
                for (int r = 0; r < 4; ++r)
                    o[n][r] *= resc[r];
            // P (D-frag layout) -> LDS [q][k] for A-frag reads
            #pragma unroll
            for (int j = 0; j < 4; ++j)
                #pragma unroll
                for (int r = 0; r < 4; ++r) {
                    int prow = lg*4 + r;
                    lP[w][prow*LPP + j*16 + lr] = f2bf(sf[j][r]);
                }
            asm volatile("" ::: "memory");         // fence ushort-write / bf16x8-read aliasing
            bf16x8 pf[2];
            #pragma unroll
            for (int kk = 0; kk < 2; ++kk)
                pf[kk] = *(const bf16x8*)&lP[w][lr*LPP + kk*32 + lg*8];
            #pragma unroll
            for (int n = 0; n < 8; ++n)
                #pragma unroll
                for (int kk = 0; kk < 2; ++kk) {
                    bf16x8 vf = *(const bf16x8*)&lV[(n*16+lr)*LVP + kk*32 + lg*8];
                    o[n] = __builtin_amdgcn_mfma_f32_16x16x32_bf16(pf[kk], vf, o[n], 0, 0, 0);
                }
        }
    }

    const int b = bh >> 3, h = bh & 7;
    #pragma unroll
    for (int n = 0; n < 8; ++n)
        #pragma unroll
        for (int r = 0; r < 4; ++r) {
            int qrow = q0 + lg*4 + r;
            int d = n*16 + lr;
            float val = o[n][r] / lsum[r];
            Y[((size_t)(b*T_SEQ + qrow))*DIM + h*HD + d] = f2bf(val);
        }
}

// ---------------------------------------------------------------- launch
extern "C" void kernel_launch(void* const* d_in, const int* in_sizes, int n_in,
                              void* d_out, int out_size, void* d_ws, size_t ws_size,
                              hipStream_t stream) {
    const float* x      = (const float*)d_in[0];
    const float* ve     = (const float*)d_in[1];
    const float* lam    = (const float*)d_in[2];
    const float* qkvw   = (const float*)d_in[3];
    const float* cprojw = (const float*)d_in[4];
    float* out = (float*)d_out;

    char* ws = (char*)d_ws;
    unsigned short* xb  = (unsigned short*)(ws);                 // 8192x1024 bf16
    unsigned short* wqb = (unsigned short*)(ws + 16777216);      // 3072x1024
    unsigned short* cpb = (unsigned short*)(ws + 23068672);      // 1024x1024
    unsigned short* qkv = (unsigned short*)(ws + 25165824);      // 8192x3072
    unsigned short* qa  = (unsigned short*)(ws + 75497472);      // [bh][t][d]
    unsigned short* ka  = (unsigned short*)(ws + 92274688);      // [bh][t][d]
    unsigned short* vt  = (unsigned short*)(ws + 109051904);     // [bh][d][t]
    unsigned short* ya  = (unsigned short*)(ws + 125829120);     // 8192x1024

    cvt_f32_bf16<<<8192, 256, 0, stream>>>(x, xb, 2097152);
    cvt_f32_bf16<<<3072, 256, 0, stream>>>(qkvw, wqb, 786432);
    cvt_f32_bf16<<<1024, 256, 0, stream>>>(cprojw, cpb, 262144);

    gemm_bt<0><<<dim3(24, 64), 256, 0, stream>>>(xb, wqb, qkv, NTOK, QKV_N, DIM);
    qkv_post<<<16384, 256, 0, stream>>>(qkv, ve, lam, qa, ka, vt);
    attn_fwd<<<dim3(32, 32), 256, 0, stream>>>(qa, ka, vt, ya);
    gemm_bt<1><<<dim3(8, 64), 256, 0, stream>>>(ya, cpb, out, NTOK, DIM, DIM);
}

// Round 2
// 209.004 us; speedup vs baseline: 1.6320x; 1.6320x over previous
//
#include <hip/hip_runtime.h>

#define DIM 1024
#define NH 8
#define HD 128
#define T_SEQ 2048
#define NTOK 8192
#define QKV_N 3072
#define ATTN_SCALE 0.12f
#define RMS_EPS 1.1920929e-07f

using f32x4  = __attribute__((ext_vector_type(4))) float;
using bf16x8 = __attribute__((ext_vector_type(8))) __bf16;

__device__ __forceinline__ unsigned short f2bf(float f) {
    unsigned int u = __builtin_bit_cast(unsigned int, f);
    u += 0x7fffu + ((u >> 16) & 1u);           // RNE
    return (unsigned short)(u >> 16);
}
__device__ __forceinline__ float bf2f(unsigned short s) {
    unsigned int u = ((unsigned int)s) << 16;
    return __builtin_bit_cast(float, u);
}

// async global->LDS, 16B per lane; dest must be wave-uniform base (+lane*16 by HW)
__device__ __forceinline__ void gll16(const void* g, void* l) {
    __builtin_amdgcn_global_load_lds(
        (const __attribute__((address_space(1))) unsigned int*)g,
        (__attribute__((address_space(3))) unsigned int*)l, 16, 0, 0);
}

// ---------------------------------------------------------------- conversions
__global__ __launch_bounds__(256) void cvt_f32_bf16(const float* __restrict__ in,
                                                    unsigned short* __restrict__ out,
                                                    int n4) {
    int i = blockIdx.x * 256 + threadIdx.x;
    if (i < n4) {
        float4 f = ((const float4*)in)[i];
        ushort4 o;
        o.x = f2bf(f.x); o.y = f2bf(f.y); o.z = f2bf(f.z); o.w = f2bf(f.w);
        ((ushort4*)out)[i] = o;
    }
}

// ---------------------------------------------------------------- GEMM  C = A * B^T
// m97 structure: 128x128 tile, BK=32, linear LDS [128][32], global_load_lds x16.
template<int OUTF32>
__global__ __launch_bounds__(256) void gemm_bt(const unsigned short* __restrict__ A,
                                               const unsigned short* __restrict__ B,
                                               void* __restrict__ Cout,
                                               int M, int N, int K) {
    __shared__ unsigned short lA[128*32];
    __shared__ unsigned short lB[128*32];
    const int tid  = threadIdx.x;
    const int lane = tid & 63;
    const int w    = tid >> 6;
    const int wm   = w >> 1, wn = w & 1;
    const int lr   = lane & 15, lg = lane >> 4;
    const int m0   = blockIdx.y * 128;
    const int n0   = blockIdx.x * 128;
    const int srow = lane >> 2;        // row within 16-row chunk
    const int scol = (lane & 3) * 8;   // element col within 32

    f32x4 acc[4][4] = {};

    for (int k0 = 0; k0 < K; k0 += 32) {
        __syncthreads();
        #pragma unroll
        for (int i = 0; i < 2; ++i) {
            int c = w*2 + i;           // chunk 0..7, 16 rows each
            gll16(&A[(size_t)(m0 + c*16 + srow)*K + k0 + scol], &lA[c*512]);
            gll16(&B[(size_t)(n0 + c*16 + srow)*K + k0 + scol], &lB[c*512]);
        }
        __syncthreads();
        bf16x8 af[4], bfr[4];
        #pragma unroll
        for (int i = 0; i < 4; ++i)
            af[i]  = *(const bf16x8*)&lA[(wm*64 + i*16 + lr)*32 + lg*8];
        #pragma unroll
        for (int j = 0; j < 4; ++j)
            bfr[j] = *(const bf16x8*)&lB[(wn*64 + j*16 + lr)*32 + lg*8];
        #pragma unroll
        for (int i = 0; i < 4; ++i)
            #pragma unroll
            for (int j = 0; j < 4; ++j)
                acc[i][j] = __builtin_amdgcn_mfma_f32_16x16x32_bf16(af[i], bfr[j], acc[i][j], 0, 0, 0);
    }

    #pragma unroll
    for (int i = 0; i < 4; ++i)
        #pragma unroll
        for (int j = 0; j < 4; ++j)
            #pragma unroll
            for (int r = 0; r < 4; ++r) {
                int row = m0 + wm*64 + i*16 + lg*4 + r;
                int col = n0 + wn*64 + j*16 + lr;
                if (OUTF32) ((float*)Cout)[(size_t)row*N + col] = acc[i][j][r];
                else ((unsigned short*)Cout)[(size_t)row*N + col] = f2bf(acc[i][j][r]);
            }
}

// ---------------------------------------------------------------- q/k post: RMSNorm + RoPE (+0.12 fold into q)
__global__ __launch_bounds__(256) void qkv_post(const unsigned short* __restrict__ qkv,
                                                unsigned short* __restrict__ qO,
                                                unsigned short* __restrict__ kO) {
    int gw   = (blockIdx.x * 256 + threadIdx.x) >> 6;
    int lane = threadIdx.x & 63;
    int h     = gw & 7;
    int token = gw >> 3;
    int t     = token & (T_SEQ-1);
    int b     = token >> 11;

    const unsigned short* base = qkv + (size_t)token * QKV_N + h*HD;
    float q1 = bf2f(base[lane]),        q2 = bf2f(base[lane+64]);
    float k1 = bf2f(base[1024+lane]),   k2 = bf2f(base[1024+lane+64]);

    float sq = q1*q1 + q2*q2;
    float sk = k1*k1 + k2*k2;
    #pragma unroll
    for (int m = 1; m < 64; m <<= 1) {
        sq += __shfl_xor(sq, m);
        sk += __shfl_xor(sk, m);
    }
    float qs = rsqrtf(sq * (1.0f/128.0f) + RMS_EPS) * ATTN_SCALE;   // fold attn scale into q
    float ks = rsqrtf(sk * (1.0f/128.0f) + RMS_EPS);
    q1 *= qs; q2 *= qs; k1 *= ks; k2 *= ks;

    float theta = (lane < 32) ? (float)t * exp2f((float)lane * (-10.0f/31.0f)) : 0.0f;
    float sn, cs;
    sincosf(theta, &sn, &cs);
    float qy1 =  q1*cs + q2*sn, qy2 = -q1*sn + q2*cs;
    float ky1 =  k1*cs + k2*sn, ky2 = -k1*sn + k2*cs;

    size_t obase = ((size_t)(b*NH + h) * T_SEQ + t) * HD;
    qO[obase + lane]      = f2bf(qy1);
    qO[obase + lane + 64] = f2bf(qy2);
    kO[obase + lane]      = f2bf(ky1);
    kO[obase + lane + 64] = f2bf(ky2);
}

// ---------------------------------------------------------------- v-mix + transpose to [bh][d][t]
__global__ __launch_bounds__(256) void vmix_t(const unsigned short* __restrict__ qkv,
                                              const float* __restrict__ ve,
                                              const float* __restrict__ lam,
                                              unsigned short* __restrict__ vt) {
    __shared__ unsigned short lT[128*72];
    const int tid = threadIdx.x;
    const int t0  = blockIdx.x * 64;
    const int bh  = blockIdx.y;
    const int b = bh >> 3, h = bh & 7;
    const float l0 = lam[0], l1 = lam[1];

    #pragma unroll
    for (int it = 0; it < 4; ++it) {
        int g  = it*256 + tid;
        int t  = g >> 4;
        int d8 = (g & 15) << 3;
        size_t token = (size_t)b*T_SEQ + t0 + t;
        ushort4 v0 = *(const ushort4*)&qkv[token*QKV_N + 2048 + h*HD + d8];
        ushort4 v1 = *(const ushort4*)&qkv[token*QKV_N + 2048 + h*HD + d8 + 4];
        float4 e0 = *(const float4*)&ve[token*DIM + h*HD + d8];
        float4 e1 = *(const float4*)&ve[token*DIM + h*HD + d8 + 4];
        lT[(d8+0)*72 + t] = f2bf(l0*bf2f(v0.x) + l1*e0.x);
        lT[(d8+1)*72 + t] = f2bf(l0*bf2f(v0.y) + l1*e0.y);
        lT[(d8+2)*72 + t] = f2bf(l0*bf2f(v0.z) + l1*e0.z);
        lT[(d8+3)*72 + t] = f2bf(l0*bf2f(v0.w) + l1*e0.w);
        lT[(d8+4)*72 + t] = f2bf(l0*bf2f(v1.x) + l1*e1.x);
        lT[(d8+5)*72 + t] = f2bf(l0*bf2f(v1.y) + l1*e1.y);
        lT[(d8+6)*72 + t] = f2bf(l0*bf2f(v1.z) + l1*e1.z);
        lT[(d8+7)*72 + t] = f2bf(l0*bf2f(v1.w) + l1*e1.w);
    }
    __syncthreads();
    #pragma unroll
    for (int it = 0; it < 4; ++it) {
        int g  = it*256 + tid;
        int d  = g >> 3;
        int t8 = (g & 7) << 3;
        uint4 pk = *(const uint4*)&lT[d*72 + t8];
        *(uint4*)&vt[((size_t)bh*HD + d)*T_SEQ + t0 + t8] = pk;
    }
}

// ---------------------------------------------------------------- flash attention (paired q-tiles, max-free softmax)
__global__ __launch_bounds__(256) void attn_fwd(const unsigned short* __restrict__ Q,
                                                const unsigned short* __restrict__ K,
                                                const unsigned short* __restrict__ Vt,
                                                unsigned short* __restrict__ Y) {
    __shared__ unsigned short lK[64*128];     // [k][d], XOR-swizzled cols
    __shared__ unsigned short lV[128*64];     // [d][k], XOR-swizzled cols
    __shared__ unsigned short lP[4][16*72];   // per-wave [q][k]

    const int tid  = threadIdx.x;
    const int lane = tid & 63;
    const int w    = tid >> 6;
    const int lr   = lane & 15, lg = lane >> 4;

    // XCD-chunked mapping: 16 blocks of one bh -> one lin%8 class (same XCD)
    const int lin = blockIdx.y * 16 + blockIdx.x;       // 0..511
    const int bh  = (lin & 7)*4 + ((lin >> 3) & 3);
    const int p   = lin >> 5;                           // 0..15
    const int qtA = p, qtB = 31 - p;

    const unsigned short* Qg = Q  + (size_t)bh * T_SEQ * HD;
    const unsigned short* Kg = K  + (size_t)bh * T_SEQ * HD;
    const unsigned short* Vg = Vt + (size_t)bh * HD * T_SEQ;
    const int q0A = qtA*64 + w*16;
    const int q0B = qtB*64 + w*16;

    bf16x8 qfA[4], qfB[4];
    #pragma unroll
    for (int kk = 0; kk < 4; ++kk) {
        qfA[kk] = *(const bf16x8*)&Qg[(size_t)(q0A + lr)*HD + kk*32 + lg*8];
        qfB[kk] = *(const bf16x8*)&Qg[(size_t)(q0B + lr)*HD + kk*32 + lg*8];
    }

    f32x4 oA[8] = {}, oB[8] = {};
    float psA[4] = {0.f,0.f,0.f,0.f}, psB[4] = {0.f,0.f,0.f,0.f};

    auto pass = [&](const bf16x8* qf, f32x4* o, float* ps, int q0, bool diag, int kbase) {
        f32x4 sf[4];
        #pragma unroll
        for (int j = 0; j < 4; ++j) {
            f32x4 s = {0.f,0.f,0.f,0.f};
            #pragma unroll
            for (int kk = 0; kk < 4; ++kk) {
                bf16x8 kf = *(const bf16x8*)&lK[(j*16+lr)*128 + ((kk*32 + lg*8) ^ ((lr&7)<<3))];
                s = __builtin_amdgcn_mfma_f32_16x16x32_bf16(qf[kk], kf, s, 0, 0, 0);
            }
            sf[j] = s;
        }
        if (diag) {
            #pragma unroll
            for (int j = 0; j < 4; ++j)
                #pragma unroll
                for (int r = 0; r < 4; ++r) {
                    int kcol = kbase + j*16 + lr;
                    int qrow = q0 + lg*4 + r;
                    if (kcol > qrow) sf[j][r] = -INFINITY;
                }
        }
        #pragma unroll
        for (int j = 0; j < 4; ++j)
            #pragma unroll
            for (int r = 0; r < 4; ++r) {
                float pp = __expf(sf[j][r]);      // bounded: |S| <= 15.36
                sf[j][r] = pp;
                ps[r] += pp;                      // per-lane partial; reduced once at end
            }
        #pragma unroll
        for (int j = 0; j < 4; ++j)
            #pragma unroll
            for (int r = 0; r < 4; ++r)
                lP[w][(lg*4+r)*72 + j*16 + lr] = f2bf(sf[j][r]);
        asm volatile("" ::: "memory");
        bf16x8 pf0 = *(const bf16x8*)&lP[w][lr*72 + lg*8];
        bf16x8 pf1 = *(const bf16x8*)&lP[w][lr*72 + 32 + lg*8];
        #pragma unroll
        for (int n = 0; n < 8; ++n) {
            bf16x8 vf0 = *(const bf16x8*)&lV[(n*16+lr)*64 + (( 0 + lg*8) ^ ((lr&7)<<3))];
            o[n] = __builtin_amdgcn_mfma_f32_16x16x32_bf16(pf0, vf0, o[n], 0, 0, 0);
            bf16x8 vf1 = *(const bf16x8*)&lV[(n*16+lr)*64 + ((32 + lg*8) ^ ((lr&7)<<3))];
            o[n] = __builtin_amdgcn_mfma_f32_16x16x32_bf16(pf1, vf1, o[n], 0, 0, 0);
        }
    };

    for (int kt = 0; kt <= qtB; ++kt) {
        const int kbase = kt * 64;
        __syncthreads();
        #pragma unroll
        for (int i = 0; i < 4; ++i) {
            int c = w*4 + i;                           // chunk 0..15
            {   // K: 4 rows x 128 cols per chunk; pre-swizzled source
                int row = c*4 + (lane >> 4);
                int col = ((lane & 15) << 3) ^ ((row & 7) << 3);
                gll16(&Kg[(size_t)(kbase + row)*HD + col], &lK[c*512]);
            }
            {   // V: 8 rows x 64 cols per chunk; pre-swizzled source
                int row = c*8 + (lane >> 3);
                int col = ((lane & 7) << 3) ^ ((row & 7) << 3);
                gll16(&Vg[(size_t)row*T_SEQ + kbase + col], &lV[c*512]);
            }
        }
        __syncthreads();
        if (kt <= qtA) pass(qfA, oA, psA, q0A, kt == qtA, kbase);
        pass(qfB, oB, psB, q0B, kt == qtB, kbase);
    }

    #pragma unroll
    for (int m = 1; m < 16; m <<= 1)
        #pragma unroll
        for (int r = 0; r < 4; ++r) {
            psA[r] += __shfl_xor(psA[r], m);
            psB[r] += __shfl_xor(psB[r], m);
        }

    const int b = bh >> 3, h = bh & 7;
    #pragma unroll
    for (int n = 0; n < 8; ++n)
        #pragma unroll
        for (int r = 0; r < 4; ++r) {
            int d = n*16 + lr;
            int qrowA = q0A + lg*4 + r;
            int qrowB = q0B + lg*4 + r;
            Y[((size_t)(b*T_SEQ + qrowA))*DIM + h*HD + d] = f2bf(oA[n][r] / psA[r]);
            Y[((size_t)(b*T_SEQ + qrowB))*DIM + h*HD + d] = f2bf(oB[n][r] / psB[r]);
        }
}

// ---------------------------------------------------------------- launch
extern "C" void kernel_launch(void* const* d_in, const int* in_sizes, int n_in,
                              void* d_out, int out_size, void* d_ws, size_t ws_size,
                              hipStream_t stream) {
    const float* x      = (const float*)d_in[0];
    const float* ve     = (const float*)d_in[1];
    const float* lam    = (const float*)d_in[2];
    const float* qkvw   = (const float*)d_in[3];
    const float* cprojw = (const float*)d_in[4];

    char* ws = (char*)d_ws;
    unsigned short* xb  = (unsigned short*)(ws);                 // 8192x1024 bf16
    unsigned short* wqb = (unsigned short*)(ws + 16777216);      // 3072x1024
    unsigned short* cpb = (unsigned short*)(ws + 23068672);      // 1024x1024
    unsigned short* qkv = (unsigned short*)(ws + 25165824);      // 8192x3072
    unsigned short* qa  = (unsigned short*)(ws + 75497472);      // [bh][t][d]
    unsigned short* ka  = (unsigned short*)(ws + 92274688);      // [bh][t][d]
    unsigned short* vt  = (unsigned short*)(ws + 109051904);     // [bh][d][t]
    unsigned short* ya  = (unsigned short*)(ws + 125829120);     // 8192x1024

    cvt_f32_bf16<<<8192, 256, 0, stream>>>(x, xb, 2097152);
    cvt_f32_bf16<<<3072, 256, 0, stream>>>(qkvw, wqb, 786432);
    cvt_f32_bf16<<<1024, 256, 0, stream>>>(cprojw, cpb, 262144);

    gemm_bt<0><<<dim3(24, 64), 256, 0, stream>>>(xb, wqb, qkv, NTOK, QKV_N, DIM);
    qkv_post<<<16384, 256, 0, stream>>>(qkv, qa, ka);
    vmix_t<<<dim3(32, 32), 256, 0, stream>>>(qkv, ve, lam, vt);
    attn_fwd<<<dim3(16, 32), 256, 0, stream>>>(qa, ka, vt, ya);
    gemm_bt<1><<<dim3(8, 64), 256, 0, stream>>>(ya, cpb, (float*)d_out, NTOK, DIM, DIM);
}

// Round 3
// 202.138 us; speedup vs baseline: 1.6874x; 1.0340x over previous
//
#include <hip/hip_runtime.h>

#define DIM 1024
#define NH 8
#define HD 128
#define T_SEQ 2048
#define NTOK 8192
#define QKV_N 3072
#define ATTN_SCALE 0.12f
#define RMS_EPS 1.1920929e-07f

using f32x4  = __attribute__((ext_vector_type(4))) float;
using bf16x8 = __attribute__((ext_vector_type(8))) __bf16;

__device__ __forceinline__ unsigned short f2bf(float f) {
    unsigned int u = __builtin_bit_cast(unsigned int, f);
    u += 0x7fffu + ((u >> 16) & 1u);           // RNE
    return (unsigned short)(u >> 16);
}
__device__ __forceinline__ float bf2f(unsigned short s) {
    unsigned int u = ((unsigned int)s) << 16;
    return __builtin_bit_cast(float, u);
}

// async global->LDS, 16B/lane; LDS dest = wave-uniform base + lane*16 (HW)
__device__ __forceinline__ void gll16(const void* g, void* l) {
    __builtin_amdgcn_global_load_lds(
        (const __attribute__((address_space(1))) unsigned int*)g,
        (__attribute__((address_space(3))) unsigned int*)l, 16, 0, 0);
}

#define VMCNT(n) asm volatile("s_waitcnt vmcnt(" #n ")" ::: "memory")

// ---------------------------------------------------------------- conversions
__global__ __launch_bounds__(256) void cvt_f32_bf16(const float* __restrict__ in,
                                                    unsigned short* __restrict__ out,
                                                    int n4) {
    int i = blockIdx.x * 256 + threadIdx.x;
    if (i < n4) {
        float4 f = ((const float4*)in)[i];
        ushort4 o;
        o.x = f2bf(f.x); o.y = f2bf(f.y); o.z = f2bf(f.z); o.w = f2bf(f.w);
        ((ushort4*)out)[i] = o;
    }
}

// ---------------------------------------------------------------- GEMM  C = A * B^T
// 256x128 tile, BK=64, 8 waves (4x2), ring-3 LDS pipeline, counted vmcnt,
// XOR-swizzled 128B rows, raw barriers, LDS-transpose epilogue.
#define GBM 256
#define GBN 128
#define GBK 64
#define SLOT_A 32768
#define SLOT_SZ 49152

template<int OUTF32>
__global__ __launch_bounds__(512, 1) void gemm256(const unsigned short* __restrict__ A,
                                                  const unsigned short* __restrict__ B,
                                                  void* __restrict__ Cout,
                                                  int M, int N, int K, int nbn) {
    __shared__ __align__(16) char smem[147456];
    const int tid  = threadIdx.x;
    const int lane = tid & 63;
    const int w    = tid >> 6;
    const int wm   = w >> 1, wn = w & 1;          // 4x2 wave grid, 64x64 per wave
    const int lr   = lane & 15, lg = lane >> 4;
    const int xsw  = (lr & 7) << 3;               // read-side XOR (elements)

    // XCD-bijective swizzle (grid % 8 == 0 for both call sites)
    const int chunk = gridDim.x >> 3;
    const int bid2  = (blockIdx.x & 7) * chunk + (blockIdx.x >> 3);
    const int m0 = (bid2 / nbn) * GBM;
    const int n0 = (bid2 % nbn) * GBN;

    const int rsub = lane >> 3;                   // staging row-within-chunk
    const int csw  = ((lane & 7) ^ rsub) << 3;    // pre-swizzled source col (elems)

    char* s0 = smem;
    char* s1 = smem + SLOT_SZ;
    char* s2 = smem + 2*SLOT_SZ;

    auto stage = [&](int kt, char* slot) {
        const int kb = kt * GBK;
        #pragma unroll
        for (int i = 0; i < 4; ++i) {             // A: 32 chunks of 8 rows x 128B
            int c = w*4 + i;
            gll16(&A[(size_t)(m0 + c*8 + rsub)*K + kb + csw], slot + c*1024);
        }
        #pragma unroll
        for (int i = 0; i < 2; ++i) {             // B: 16 chunks
            int c = w*2 + i;
            gll16(&B[(size_t)(n0 + c*8 + rsub)*K + kb + csw], slot + SLOT_A + c*1024);
        }
    };

    f32x4 acc[4][4] = {};
    const int KT = K / GBK;

    stage(0, s0);
    stage(1, s1);
    VMCNT(6);                                     // tile0 landed; tile1 in flight
    __builtin_amdgcn_s_barrier();
    __builtin_amdgcn_sched_barrier(0);

    for (int t = 0; t < KT; ++t) {
        if (t + 2 < KT) stage(t + 2, s2);         // slot of t-1, freed at last barrier
        const unsigned short* sA = (const unsigned short*)s0;
        const unsigned short* sB = (const unsigned short*)(s0 + SLOT_A);
        bf16x8 bfr[4][2];
        #pragma unroll
        for (int n = 0; n < 4; ++n)
            #pragma unroll
            for (int kk = 0; kk < 2; ++kk)
                bfr[n][kk] = *(const bf16x8*)&sB[(wn*64 + n*16 + lr)*64 + ((kk*32 + lg*8) ^ xsw)];
        #pragma unroll
        for (int m = 0; m < 4; ++m) {
            bf16x8 af[2];
            #pragma unroll
            for (int kk = 0; kk < 2; ++kk)
                af[kk] = *(const bf16x8*)&sA[(wm*64 + m*16 + lr)*64 + ((kk*32 + lg*8) ^ xsw)];
            __builtin_amdgcn_s_setprio(1);
            #pragma unroll
            for (int n = 0; n < 4; ++n)
                #pragma unroll
                for (int kk = 0; kk < 2; ++kk)
                    acc[m][n] = __builtin_amdgcn_mfma_f32_16x16x32_bf16(af[kk], bfr[n][kk], acc[m][n], 0, 0, 0);
            __builtin_amdgcn_s_setprio(0);
        }
        if (t + 2 < KT) { VMCNT(6); }             // t+1 complete, t+2's 6 in flight
        else            { VMCNT(0); }             // tail drain
        __builtin_amdgcn_s_barrier();
        __builtin_amdgcn_sched_barrier(0);
        char* tmp = s0; s0 = s1; s1 = s2; s2 = tmp;
    }

    __syncthreads();                              // protect scratch overlay
    float* sc = (float*)(smem + (size_t)w * 17408);   // 64 x 68 f32 per wave
    #pragma unroll
    for (int m = 0; m < 4; ++m)
        #pragma unroll
        for (int n = 0; n < 4; ++n)
            #pragma unroll
            for (int r = 0; r < 4; ++r)
                sc[(m*16 + lg*4 + r)*68 + n*16 + lr] = acc[m][n][r];

    if (OUTF32) {
        float* C = (float*)Cout;
        #pragma unroll
        for (int rnd = 0; rnd < 16; ++rnd) {
            int g = rnd*64 + lane;
            int row = g >> 4, c4 = (g & 15) * 4;
            float4 v = *(float4*)&sc[row*68 + c4];
            *(float4*)&C[(size_t)(m0 + wm*64 + row)*N + n0 + wn*64 + c4] = v;
        }
    } else {
        unsigned short* C = (unsigned short*)Cout;
        #pragma unroll
        for (int rnd = 0; rnd < 8; ++rnd) {
            int g = rnd*64 + lane;
            int row = g >> 3, c8 = (g & 7) * 8;
            float4 v0 = *(float4*)&sc[row*68 + c8];
            float4 v1 = *(float4*)&sc[row*68 + c8 + 4];
            uint4 o;
            o.x = f2bf(v0.x) | ((unsigned)f2bf(v0.y) << 16);
            o.y = f2bf(v0.z) | ((unsigned)f2bf(v0.w) << 16);
            o.z = f2bf(v1.x) | ((unsigned)f2bf(v1.y) << 16);
            o.w = f2bf(v1.z) | ((unsigned)f2bf(v1.w) << 16);
            *(uint4*)&C[(size_t)(m0 + wm*64 + row)*N + n0 + wn*64 + c8] = o;
        }
    }
}

// ---------------------------------------------------------------- q/k post: RMSNorm + RoPE (+0.12 fold into q)
__global__ __launch_bounds__(256) void qkv_post(const unsigned short* __restrict__ qkv,
                                                unsigned short* __restrict__ qO,
                                                unsigned short* __restrict__ kO) {
    int gw   = (blockIdx.x * 256 + threadIdx.x) >> 6;
    int lane = threadIdx.x & 63;
    int h     = gw & 7;
    int token = gw >> 3;
    int t     = token & (T_SEQ-1);
    int b     = token >> 11;

    const unsigned short* base = qkv + (size_t)token * QKV_N + h*HD;
    float q1 = bf2f(base[lane]),        q2 = bf2f(base[lane+64]);
    float k1 = bf2f(base[1024+lane]),   k2 = bf2f(base[1024+lane+64]);

    float sq = q1*q1 + q2*q2;
    float sk = k1*k1 + k2*k2;
    #pragma unroll
    for (int m = 1; m < 64; m <<= 1) {
        sq += __shfl_xor(sq, m);
        sk += __shfl_xor(sk, m);
    }
    float qs = rsqrtf(sq * (1.0f/128.0f) + RMS_EPS) * ATTN_SCALE;
    float ks = rsqrtf(sk * (1.0f/128.0f) + RMS_EPS);
    q1 *= qs; q2 *= qs; k1 *= ks; k2 *= ks;

    float theta = (lane < 32) ? (float)t * exp2f((float)lane * (-10.0f/31.0f)) : 0.0f;
    float sn, cs;
    sincosf(theta, &sn, &cs);
    float qy1 =  q1*cs + q2*sn, qy2 = -q1*sn + q2*cs;
    float ky1 =  k1*cs + k2*sn, ky2 = -k1*sn + k2*cs;

    size_t obase = ((size_t)(b*NH + h) * T_SEQ + t) * HD;
    qO[obase + lane]      = f2bf(qy1);
    qO[obase + lane + 64] = f2bf(qy2);
    kO[obase + lane]      = f2bf(ky1);
    kO[obase + lane + 64] = f2bf(ky2);
}

// ---------------------------------------------------------------- v-mix + transpose to [bh][d][t]
__global__ __launch_bounds__(256) void vmix_t(const unsigned short* __restrict__ qkv,
                                              const float* __restrict__ ve,
                                              const float* __restrict__ lam,
                                              unsigned short* __restrict__ vt) {
    __shared__ unsigned short lT[128*72];
    const int tid = threadIdx.x;
    const int t0  = blockIdx.x * 64;
    const int bh  = blockIdx.y;
    const int b = bh >> 3, h = bh & 7;
    const float l0 = lam[0], l1 = lam[1];

    #pragma unroll
    for (int it = 0; it < 4; ++it) {
        int g  = it*256 + tid;
        int t  = g >> 4;
        int d8 = (g & 15) << 3;
        size_t token = (size_t)b*T_SEQ + t0 + t;
        ushort4 v0 = *(const ushort4*)&qkv[token*QKV_N + 2048 + h*HD + d8];
        ushort4 v1 = *(const ushort4*)&qkv[token*QKV_N + 2048 + h*HD + d8 + 4];
        float4 e0 = *(const float4*)&ve[token*DIM + h*HD + d8];
        float4 e1 = *(const float4*)&ve[token*DIM + h*HD + d8 + 4];
        lT[(d8+0)*72 + t] = f2bf(l0*bf2f(v0.x) + l1*e0.x);
        lT[(d8+1)*72 + t] = f2bf(l0*bf2f(v0.y) + l1*e0.y);
        lT[(d8+2)*72 + t] = f2bf(l0*bf2f(v0.z) + l1*e0.z);
        lT[(d8+3)*72 + t] = f2bf(l0*bf2f(v0.w) + l1*e0.w);
        lT[(d8+4)*72 + t] = f2bf(l0*bf2f(v1.x) + l1*e1.x);
        lT[(d8+5)*72 + t] = f2bf(l0*bf2f(v1.y) + l1*e1.y);
        lT[(d8+6)*72 + t] = f2bf(l0*bf2f(v1.z) + l1*e1.z);
        lT[(d8+7)*72 + t] = f2bf(l0*bf2f(v1.w) + l1*e1.w);
    }
    __syncthreads();
    #pragma unroll
    for (int it = 0; it < 4; ++it) {
        int g  = it*256 + tid;
        int d  = g >> 3;
        int t8 = (g & 7) << 3;
        uint4 pk = *(const uint4*)&lT[d*72 + t8];
        *(uint4*)&vt[((size_t)bh*HD + d)*T_SEQ + t0 + t8] = pk;
    }
}

// ---------------------------------------------------------------- flash attention
// paired q-tiles, max-free softmax, K/V dbuf + counted vmcnt, 1 barrier/tile.
__global__ __launch_bounds__(256) void attn_fwd(const unsigned short* __restrict__ Q,
                                                const unsigned short* __restrict__ K,
                                                const unsigned short* __restrict__ Vt,
                                                unsigned short* __restrict__ Y) {
    __shared__ unsigned short lK[2][64*128];   // [k][d], XOR-swizzled
    __shared__ unsigned short lV[2][128*64];   // [d][k], XOR-swizzled
    __shared__ unsigned short lP[4][16*64];    // per-wave [q][k], XOR-swizzled

    const int tid  = threadIdx.x;
    const int lane = tid & 63;
    const int w    = tid >> 6;
    const int lr   = lane & 15, lg = lane >> 4;

    const int lin = blockIdx.y * 16 + blockIdx.x;       // 0..511
    const int bh  = (lin & 7)*4 + ((lin >> 3) & 3);
    const int p   = lin >> 5;                           // 0..15
    const int qtA = p, qtB = 31 - p;

    const unsigned short* Qg = Q  + (size_t)bh * T_SEQ * HD;
    const unsigned short* Kg = K  + (size_t)bh * T_SEQ * HD;
    const unsigned short* Vg = Vt + (size_t)bh * HD * T_SEQ;
    const int q0A = qtA*64 + w*16;
    const int q0B = qtB*64 + w*16;

    auto stage = [&](int kt, int s) {
        const int kbase = kt * 64;
        #pragma unroll
        for (int i = 0; i < 4; ++i) {          // K: 16 chunks of 4 rows x 256B
            int c = w*4 + i;
            int row = c*4 + (lane >> 4);
            int col = ((lane & 15) << 3) ^ ((row & 7) << 3);
            gll16(&Kg[(size_t)(kbase + row)*HD + col], &lK[s][c*512]);
        }
        #pragma unroll
        for (int i = 0; i < 4; ++i) {          // V: 16 chunks of 8 rows x 128B
            int c = w*4 + i;
            int row = c*8 + (lane >> 3);
            int col = ((lane & 7) << 3) ^ ((row & 7) << 3);
            gll16(&Vg[(size_t)row*T_SEQ + kbase + col], &lV[s][c*512]);
        }
    };

    bf16x8 qfA[4], qfB[4];
    #pragma unroll
    for (int kk = 0; kk < 4; ++kk) {
        qfA[kk] = *(const bf16x8*)&Qg[(size_t)(q0A + lr)*HD + kk*32 + lg*8];
        qfB[kk] = *(const bf16x8*)&Qg[(size_t)(q0B + lr)*HD + kk*32 + lg*8];
    }
    // materialize Q before pipeline so no conservative vmcnt(0) lands in the loop
    VMCNT(0);
    #pragma unroll
    for (int kk = 0; kk < 4; ++kk)
        asm volatile("" :: "v"(qfA[kk]), "v"(qfB[kk]));

    f32x4 oA[8] = {}, oB[8] = {};
    float psA[4] = {0.f,0.f,0.f,0.f}, psB[4] = {0.f,0.f,0.f,0.f};

    auto pass = [&](const bf16x8* qf, f32x4* o, float* ps, int q0, bool diag,
                    int kbase, const unsigned short* lKc, const unsigned short* lVc) {
        f32x4 sf[4];
        #pragma unroll
        for (int j = 0; j < 4; ++j) {
            f32x4 s = {0.f,0.f,0.f,0.f};
            __builtin_amdgcn_s_setprio(1);
            #pragma unroll
            for (int kk = 0; kk < 4; ++kk) {
                bf16x8 kf = *(const bf16x8*)&lKc[(j*16+lr)*128 + ((kk*32 + lg*8) ^ ((lr&7)<<3))];
                s = __builtin_amdgcn_mfma_f32_16x16x32_bf16(qf[kk], kf, s, 0, 0, 0);
            }
            __builtin_amdgcn_s_setprio(0);
            sf[j] = s;
        }
        if (diag) {
            #pragma unroll
            for (int j = 0; j < 4; ++j)
                #pragma unroll
                for (int r = 0; r < 4; ++r) {
                    int kcol = kbase + j*16 + lr;
                    int qrow = q0 + lg*4 + r;
                    if (kcol > qrow) sf[j][r] = -INFINITY;
                }
        }
        #pragma unroll
        for (int j = 0; j < 4; ++j)
            #pragma unroll
            for (int r = 0; r < 4; ++r) {
                float pp = __expf(sf[j][r]);      // bounded: |S| <= 15.36
                sf[j][r] = pp;
                ps[r] += pp;
            }
        #pragma unroll
        for (int j = 0; j < 4; ++j)
            #pragma unroll
            for (int r = 0; r < 4; ++r) {
                int prow = lg*4 + r;
                lP[w][prow*64 + ((j*16 + lr) ^ ((prow&7)<<3))] = f2bf(sf[j][r]);
            }
        asm volatile("" ::: "memory");
        bf16x8 pf[2];
        #pragma unroll
        for (int kk = 0; kk < 2; ++kk)
            pf[kk] = *(const bf16x8*)&lP[w][lr*64 + ((kk*32 + lg*8) ^ ((lr&7)<<3))];
        #pragma unroll
        for (int n = 0; n < 8; ++n) {
            __builtin_amdgcn_s_setprio(1);
            #pragma unroll
            for (int kk = 0; kk < 2; ++kk) {
                bf16x8 vf = *(const bf16x8*)&lVc[(n*16+lr)*64 + ((kk*32 + lg*8) ^ ((lr&7)<<3))];
                o[n] = __builtin_amdgcn_mfma_f32_16x16x32_bf16(pf[kk], vf, o[n], 0, 0, 0);
            }
            __builtin_amdgcn_s_setprio(0);
        }
    };

    stage(0, 0);
    for (int kt = 0; kt <= qtB; ++kt) {
        __builtin_amdgcn_s_barrier();              // all waves done with buf[(kt+1)&1]
        const bool pre = (kt + 1 <= qtB);
        if (pre) stage(kt + 1, (kt + 1) & 1);
        if (pre) { VMCNT(8); }                     // tile kt landed; kt+1 in flight
        else     { VMCNT(0); }
        __builtin_amdgcn_sched_barrier(0);
        const int kbase = kt * 64;
        const unsigned short* lKc = lK[kt & 1];
        const unsigned short* lVc = lV[kt & 1];
        if (kt <= qtA) pass(qfA, oA, psA, q0A, kt == qtA, kbase, lKc, lVc);
        pass(qfB, oB, psB, q0B, kt == qtB, kbase, lKc, lVc);
    }

    #pragma unroll
    for (int m = 1; m < 16; m <<= 1)
        #pragma unroll
        for (int r = 0; r < 4; ++r) {
            psA[r] += __shfl_xor(psA[r], m);
            psB[r] += __shfl_xor(psB[r], m);
        }
    float riA[4], riB[4];
    #pragma unroll
    for (int r = 0; r < 4; ++r) { riA[r] = 1.0f / psA[r]; riB[r] = 1.0f / psB[r]; }

    const int b = bh >> 3, h = bh & 7;
    #pragma unroll
    for (int n = 0; n < 8; ++n)
        #pragma unroll
        for (int r = 0; r < 4; ++r) {
            int d = n*16 + lr;
            int qrowA = q0A + lg*4 + r;
            int qrowB = q0B + lg*4 + r;
            Y[((size_t)(b*T_SEQ + qrowA))*DIM + h*HD + d] = f2bf(oA[n][r] * riA[r]);
            Y[((size_t)(b*T_SEQ + qrowB))*DIM + h*HD + d] = f2bf(oB[n][r] * riB[r]);
        }
}

// ---------------------------------------------------------------- launch
extern "C" void kernel_launch(void* const* d_in, const int* in_sizes, int n_in,
                              void* d_out, int out_size, void* d_ws, size_t ws_size,
                              hipStream_t stream) {
    const float* x      = (const float*)d_in[0];
    const float* ve     = (const float*)d_in[1];
    const float* lam    = (const float*)d_in[2];
    const float* qkvw   = (const float*)d_in[3];
    const float* cprojw = (const float*)d_in[4];

    char* ws = (char*)d_ws;
    unsigned short* xb  = (unsigned short*)(ws);                 // 8192x1024 bf16
    unsigned short* wqb = (unsigned short*)(ws + 16777216);      // 3072x1024
    unsigned short* cpb = (unsigned short*)(ws + 23068672);      // 1024x1024
    unsigned short* qkv = (unsigned short*)(ws + 25165824);      // 8192x3072
    unsigned short* qa  = (unsigned short*)(ws + 75497472);      // [bh][t][d]
    unsigned short* ka  = (unsigned short*)(ws + 92274688);      // [bh][t][d]
    unsigned short* vt  = (unsigned short*)(ws + 109051904);     // [bh][d][t]
    unsigned short* ya  = (unsigned short*)(ws + 125829120);     // 8192x1024

    cvt_f32_bf16<<<8192, 256, 0, stream>>>(x, xb, 2097152);
    cvt_f32_bf16<<<3072, 256, 0, stream>>>(qkvw, wqb, 786432);
    cvt_f32_bf16<<<1024, 256, 0, stream>>>(cprojw, cpb, 262144);

    gemm256<0><<<768, 512, 0, stream>>>(xb, wqb, qkv, NTOK, QKV_N, DIM, 24);
    qkv_post<<<16384, 256, 0, stream>>>(qkv, qa, ka);
    vmix_t<<<dim3(32, 32), 256, 0, stream>>>(qkv, ve, lam, vt);
    attn_fwd<<<dim3(16, 32), 256, 0, stream>>>(qa, ka, vt, ya);
    gemm256<1><<<256, 512, 0, stream>>>(ya, cpb, (float*)d_out, NTOK, DIM, DIM, 8);
}